// Round 1
// baseline (56.579 us; speedup 1.0000x reference)
//
#include <hip/hip_runtime.h>
#include <math.h>

#define NPOINT 262144   // POINT_NUM
#define NSEG   262144   // fullpath has NPOINT+1 points -> NSEG segments
#define NVERT  17
#define NSAMP  30

struct Consts {
  float qx[NVERT], qy[NVERT], sx[NVERT], sy[NVERT];  // wzy: vertex + edge vector
  float dx[NVERT], dy[NVERT], c0[NVERT];             // fxy: unit normal + offset (0.1 - q.d)
  float fr[NSAMP];                                   // sample fractions
};

__launch_bounds__(256, 4)
__global__ void path_cost_kernel(const float2* __restrict__ path,
                                 const float2* __restrict__ st,
                                 const float2* __restrict__ en,
                                 float* __restrict__ out,
                                 Consts K) {
  const int i = blockIdx.x * 256 + threadIdx.x;   // segment id, grid covers exactly
  float wzy = 0.f, fxy = 0.f, lp = 0.f;
  {
    float2 a = (i == 0)        ? *st : path[i - 1];
    float2 b = (i == NSEG - 1) ? *en : path[i];
    const float rx = b.x - a.x, ry = b.y - a.y;
    lp = sqrtf(fmaf(ry, ry, fmaf(rx, rx, 1e-6f)));

    // ---- wzy: segment-edge intersection count ----
    // t = nt/den, u = nu/den ; indicator(0<t<1 && 0<u<1) without dividing:
    //   0<t<1  <=>  nt*den > 0  &&  (nt-den)*den < 0
    #pragma unroll
    for (int e = 0; e < NVERT; ++e) {
      const float qpx = K.qx[e] - a.x;
      const float qpy = K.qy[e] - a.y;
      const float den = fmaf(rx, K.sy[e], fmaf(-ry, K.sx[e], 1e-8f));
      const float nt  = qpx * K.sy[e] - qpy * K.sx[e];
      const float nu  = qpx * ry - qpy * rx;
      const bool hit = (nt * den > 0.f) && ((nt - den) * den < 0.f) &&
                       (nu * den > 0.f) && ((nu - den) * den < 0.f);
      wzy += hit ? 1.f : 0.f;
    }

    // ---- fxy: 30 samples along the segment, relu-product per obstacle ----
    for (int k = 0; k < NSAMP; ++k) {
      const float f  = K.fr[k];
      const float px = fmaf(f, rx, a.x);
      const float py = fmaf(f, ry, a.y);
      float pr0 = 1.f, pr1 = 1.f, pr2 = 1.f, pr3 = 1.f;
      #pragma unroll
      for (int e = 0; e < 5; ++e)
        pr0 *= fmaxf(fmaf(px, K.dx[e], fmaf(py, K.dy[e], K.c0[e])), 0.f);
      #pragma unroll
      for (int e = 5; e < 10; ++e)
        pr1 *= fmaxf(fmaf(px, K.dx[e], fmaf(py, K.dy[e], K.c0[e])), 0.f);
      #pragma unroll
      for (int e = 10; e < 13; ++e)
        pr2 *= fmaxf(fmaf(px, K.dx[e], fmaf(py, K.dy[e], K.c0[e])), 0.f);
      #pragma unroll
      for (int e = 13; e < 17; ++e)
        pr3 *= fmaxf(fmaf(px, K.dx[e], fmaf(py, K.dy[e], K.c0[e])), 0.f);
      fxy += (pr0 + pr1) + (pr2 + pr3);
    }
  }

  // ---- reduction: wave64 shuffle -> LDS -> one atomic per block per output ----
  #pragma unroll
  for (int o = 32; o > 0; o >>= 1) {
    wzy += __shfl_down(wzy, o);
    fxy += __shfl_down(fxy, o);
    lp  += __shfl_down(lp,  o);
  }
  __shared__ float sm[3][4];  // 256 threads = 4 waves
  const int wid = threadIdx.x >> 6;
  if ((threadIdx.x & 63) == 0) { sm[0][wid] = wzy; sm[1][wid] = fxy; sm[2][wid] = lp; }
  __syncthreads();
  if (threadIdx.x == 0) {
    atomicAdd(&out[0], (sm[0][0] + sm[0][1]) + (sm[0][2] + sm[0][3]));
    atomicAdd(&out[1], (sm[1][0] + sm[1][1]) + (sm[1][2] + sm[1][3]));
    atomicAdd(&out[2], (sm[2][0] + sm[2][1]) + (sm[2][2] + sm[2][3]));
  }
}

extern "C" void kernel_launch(void* const* d_in, const int* in_sizes, int n_in,
                              void* d_out, int out_size, void* d_ws, size_t ws_size,
                              hipStream_t stream) {
  (void)in_sizes; (void)n_in; (void)out_size; (void)d_ws; (void)ws_size;

  static const int   cnt[4] = {5, 5, 3, 4};
  static const float VX[NVERT] = {1.23f, 1.75f, 2.1f,  1.58f, 1.4f,
                                  4.65f, 4.0f,  4.52f, 5.06f, 5.9f,
                                  6.78f, 7.78f, 7.78f,
                                  4.0f,  4.35f, 4.8f,  4.37f};
  static const float VY[NVERT] = {3.47f, 4.0f,  3.63f, 2.3f,  2.67f,
                                  5.98f, 6.48f, 7.68f, 7.73f, 6.95f,
                                  3.4f,  5.1f,  3.76f,
                                  3.0f,  3.35f, 3.45f, 2.75f};

  Consts K;
  int base = 0;
  for (int ob = 0; ob < 4; ++ob) {
    for (int j = 0; j < cnt[ob]; ++j) {
      const int e = base + j;
      const int n = base + ((j + 1) % cnt[ob]);
      const float sx = VX[n] - VX[e], sy = VY[n] - VY[e];
      K.qx[e] = VX[e]; K.qy[e] = VY[e]; K.sx[e] = sx; K.sy[e] = sy;
      float dx = sy, dy = -sx;
      const float nrm = sqrtf(dx * dx + dy * dy);
      dx /= nrm; dy /= nrm;
      K.dx[e] = dx; K.dy[e] = dy;
      K.c0[e] = 0.1f - (VX[e] * dx + VY[e] * dy);
    }
    base += cnt[ob];
  }
  K.fr[0] = 1.0f;
  for (int k = 1; k < NSAMP; ++k) K.fr[k] = (float)k / 30.0f;

  const float2* path = (const float2*)d_in[0];  // (262143, 2) f32
  const float2* st   = (const float2*)d_in[1];  // (2,) f32
  const float2* en   = (const float2*)d_in[2];  // (2,) f32
  float* out = (float*)d_out;                   // 3 f32

  hipMemsetAsync(out, 0, 3 * sizeof(float), stream);
  path_cost_kernel<<<NSEG / 256, 256, 0, stream>>>(path, st, en, out, K);
}